// Round 7
// baseline (249.238 us; speedup 1.0000x reference)
//
#include <hip/hip_runtime.h>

// QuantizedAdd: out = clip(requant(bypass) + requant(prev) + z3, -128, 127)
// B=128, CHW = 200704 int32/sample -> 50176 int4/sample = 256*7*28.
// R6: explicit 3-deep software pipeline. R4's profile showed VGPR_Count=32,
// i.e. the compiler did NOT keep the 14 issued loads in flight (56 data
// VGPRs needed) — it serialized. Pipeline depth 3 (6 loads in flight/lane,
// ~24 data VGPRs) keeps ~8 waves/SIMD occupancy AND steady per-lane MLP.
// NT loads + NT stores retained (R3 vs R4 A/B: nt loads worth ~40 us).

typedef int int4v __attribute__((ext_vector_type(4)));

constexpr int kCHW4   = (64 * 56 * 56) / 4;       // 50176
constexpr int kUnroll = 7;                        // int4 per thread
constexpr int kBlkX   = kCHW4 / (256 * kUnroll);  // 28 blocks per sample
constexpr int kPipe   = 3;                        // load-pairs in flight

// Range-narrowed gemmlowp requantize (|x-z|<=255, lsh<=2, M0 in [2^30,2^31)
// => |v|<=1020, |r|<=1021 fits int32; rounding divide + sum + clamp in int32).
__device__ __forceinline__ int requant_one(int x, int z, int M0,
                                           int lsh, int rsh) {
    const int v = (x - z) << lsh;
    const long long prod  = (long long)v * (long long)M0;
    const long long nudge = (v >= 0) ? (1LL << 30) : (1LL - (1LL << 30));
    const int r = (int)((prod + nudge) >> 31);
    const int mask = (1 << rsh) - 1;
    const int rem  = r & mask;
    const int thr  = (mask >> 1) + ((r < 0) ? 1 : 0);
    return (r >> rsh) + ((rem > thr) ? 1 : 0);
}

__device__ __forceinline__ int4v requant_add4(int4v xb, int4v xp,
                                              int zb, int M0b, int lb, int rb,
                                              int zp, int M0p, int lp, int rp,
                                              int z3v) {
    int4v o;
#pragma unroll
    for (int i = 0; i < 4; ++i) {
        const int t = requant_one(xb[i], zb, M0b, lb, rb)
                    + requant_one(xp[i], zp, M0p, lp, rp) + z3v;
        o[i] = min(max(t, -128), 127);
    }
    return o;
}

__global__ __launch_bounds__(256) void QuantizedAdd_kernel(
    const int* __restrict__ bypass, const int* __restrict__ prev,
    const int* __restrict__ batch_cluster,
    const int* __restrict__ z_bypass, const int* __restrict__ z_prev,
    const int* __restrict__ z3,
    const int* __restrict__ M0_bypass, const int* __restrict__ M0_prev,
    const int* __restrict__ shift_bypass, const int* __restrict__ shift_prev,
    int* __restrict__ out)
{
    const int b = blockIdx.y;                 // uniform per block -> SGPR
    const int c = batch_cluster[b];

    const int zb  = z_bypass[c];
    const int zp  = z_prev[c];
    const int z3v = z3[c];
    const int M0b = M0_bypass[c];
    const int M0p = M0_prev[c];
    const int sb  = shift_bypass[c];
    const int sp  = shift_prev[c];
    const int lb = (sb < 0) ? -sb : 0;
    const int rb = (sb < 0) ?   0 : sb;
    const int lp = (sp < 0) ? -sp : 0;
    const int rp = (sp < 0) ?   0 : sp;

    const int base = b * kCHW4 + blockIdx.x * (256 * kUnroll) + threadIdx.x;

    const int4v* __restrict__ pb = (const int4v*)bypass;
    const int4v* __restrict__ pp = (const int4v*)prev;
    int4v* __restrict__ po = (int4v*)out;

    // 3-deep pipeline: ring buffer of load-pairs.
    int4v xb[kPipe], xp[kPipe];
#pragma unroll
    for (int u = 0; u < kPipe; ++u) {
        xb[u] = __builtin_nontemporal_load(&pb[base + u * 256]);
        xp[u] = __builtin_nontemporal_load(&pp[base + u * 256]);
    }

#pragma unroll
    for (int u = 0; u < kUnroll; ++u) {
        const int slot = u % kPipe;
        const int4v o = requant_add4(xb[slot], xp[slot],
                                     zb, M0b, lb, rb, zp, M0p, lp, rp, z3v);
        // Prefetch pair u+kPipe into the slot just consumed, then store.
        if (u + kPipe < kUnroll) {
            xb[slot] = __builtin_nontemporal_load(&pb[base + (u + kPipe) * 256]);
            xp[slot] = __builtin_nontemporal_load(&pp[base + (u + kPipe) * 256]);
        }
        __builtin_nontemporal_store(o, &po[base + u * 256]);
    }
}

extern "C" void kernel_launch(void* const* d_in, const int* in_sizes, int n_in,
                              void* d_out, int out_size, void* d_ws, size_t ws_size,
                              hipStream_t stream) {
    const int* bypass        = (const int*)d_in[0];
    const int* prev          = (const int*)d_in[1];
    const int* batch_cluster = (const int*)d_in[2];
    const int* z_bypass      = (const int*)d_in[3];
    const int* z_prev        = (const int*)d_in[4];
    const int* z3            = (const int*)d_in[5];
    const int* M0_bypass     = (const int*)d_in[6];
    const int* M0_prev       = (const int*)d_in[7];
    const int* shift_bypass  = (const int*)d_in[8];
    const int* shift_prev    = (const int*)d_in[9];

    const int B = in_sizes[2];                  // 128
    dim3 grid(kBlkX, B, 1);                     // (28, 128) = 3584 blocks
    dim3 block(256, 1, 1);
    QuantizedAdd_kernel<<<grid, block, 0, stream>>>(
        bypass, prev, batch_cluster, z_bypass, z_prev, z3,
        M0_bypass, M0_prev, shift_bypass, shift_prev, (int*)d_out);
}

// Round 8
// 244.097 us; speedup vs baseline: 1.0211x; 1.0211x over previous
//
#include <hip/hip_runtime.h>

// QuantizedAdd: out = clip(requant(bypass) + requant(prev) + z3, -128, 127)
// B=128, CHW = 200704 int32/sample -> 50176 int4/sample = 256*4*49.
// R7: R5 policy (all loads issued before any use, NT loads + NT stores)
// with kUnroll 7 -> 4: grid (49,128)=6272 blocks (24.5/CU vs 14/CU) for
// finer tail granularity + more resident waves; 8 loads in flight/lane.

typedef int int4v __attribute__((ext_vector_type(4)));

constexpr int kCHW4   = (64 * 56 * 56) / 4;       // 50176
constexpr int kUnroll = 4;                        // int4 per thread
constexpr int kBlkX   = kCHW4 / (256 * kUnroll);  // 49 blocks per sample

// Range-narrowed gemmlowp requantize (|x-z|<=255, lsh<=2, M0 in [2^30,2^31)
// => |v|<=1020, |r|<=1021 fits int32; rounding divide + sum + clamp in int32).
__device__ __forceinline__ int requant_one(int x, int z, int M0,
                                           int lsh, int rsh) {
    const int v = (x - z) << lsh;
    const long long prod  = (long long)v * (long long)M0;
    const long long nudge = (v >= 0) ? (1LL << 30) : (1LL - (1LL << 30));
    const int r = (int)((prod + nudge) >> 31);
    const int mask = (1 << rsh) - 1;
    const int rem  = r & mask;
    const int thr  = (mask >> 1) + ((r < 0) ? 1 : 0);
    return (r >> rsh) + ((rem > thr) ? 1 : 0);
}

__device__ __forceinline__ int4v requant_add4(int4v xb, int4v xp,
                                              int zb, int M0b, int lb, int rb,
                                              int zp, int M0p, int lp, int rp,
                                              int z3v) {
    int4v o;
#pragma unroll
    for (int i = 0; i < 4; ++i) {
        const int t = requant_one(xb[i], zb, M0b, lb, rb)
                    + requant_one(xp[i], zp, M0p, lp, rp) + z3v;
        o[i] = min(max(t, -128), 127);
    }
    return o;
}

__global__ __launch_bounds__(256) void QuantizedAdd_kernel(
    const int* __restrict__ bypass, const int* __restrict__ prev,
    const int* __restrict__ batch_cluster,
    const int* __restrict__ z_bypass, const int* __restrict__ z_prev,
    const int* __restrict__ z3,
    const int* __restrict__ M0_bypass, const int* __restrict__ M0_prev,
    const int* __restrict__ shift_bypass, const int* __restrict__ shift_prev,
    int* __restrict__ out)
{
    const int b = blockIdx.y;                 // uniform per block -> SGPR
    const int c = batch_cluster[b];

    const int zb  = z_bypass[c];
    const int zp  = z_prev[c];
    const int z3v = z3[c];
    const int M0b = M0_bypass[c];
    const int M0p = M0_prev[c];
    const int sb  = shift_bypass[c];
    const int sp  = shift_prev[c];
    const int lb = (sb < 0) ? -sb : 0;
    const int rb = (sb < 0) ?   0 : sb;
    const int lp = (sp < 0) ? -sp : 0;
    const int rp = (sp < 0) ?   0 : sp;

    const int base = b * kCHW4 + blockIdx.x * (256 * kUnroll) + threadIdx.x;

    const int4v* __restrict__ pb = (const int4v*)bypass;
    const int4v* __restrict__ pp = (const int4v*)prev;
    int4v* __restrict__ po = (int4v*)out;

    // Issue ALL loads before any consumption: 8 x 1KB wave-loads in flight.
    int4v xb[kUnroll], xp[kUnroll];
#pragma unroll
    for (int u = 0; u < kUnroll; ++u)
        xb[u] = __builtin_nontemporal_load(&pb[base + u * 256]);
#pragma unroll
    for (int u = 0; u < kUnroll; ++u)
        xp[u] = __builtin_nontemporal_load(&pp[base + u * 256]);

#pragma unroll
    for (int u = 0; u < kUnroll; ++u) {
        const int4v o = requant_add4(xb[u], xp[u],
                                     zb, M0b, lb, rb, zp, M0p, lp, rp, z3v);
        __builtin_nontemporal_store(o, &po[base + u * 256]);
    }
}

extern "C" void kernel_launch(void* const* d_in, const int* in_sizes, int n_in,
                              void* d_out, int out_size, void* d_ws, size_t ws_size,
                              hipStream_t stream) {
    const int* bypass        = (const int*)d_in[0];
    const int* prev          = (const int*)d_in[1];
    const int* batch_cluster = (const int*)d_in[2];
    const int* z_bypass      = (const int*)d_in[3];
    const int* z_prev        = (const int*)d_in[4];
    const int* z3            = (const int*)d_in[5];
    const int* M0_bypass     = (const int*)d_in[6];
    const int* M0_prev       = (const int*)d_in[7];
    const int* shift_bypass  = (const int*)d_in[8];
    const int* shift_prev    = (const int*)d_in[9];

    const int B = in_sizes[2];                  // 128
    dim3 grid(kBlkX, B, 1);                     // (49, 128) = 6272 blocks
    dim3 block(256, 1, 1);
    QuantizedAdd_kernel<<<grid, block, 0, stream>>>(
        bypass, prev, batch_cluster, z_bypass, z_prev, z3,
        M0_bypass, M0_prev, shift_bypass, shift_prev, (int*)d_out);
}